// Round 14
// baseline (260.269 us; speedup 1.0000x reference)
//
#include <hip/hip_runtime.h>

#define MTOT 65536   // B*V
#define KTOT 1024    // F
#define NTOT 1024    // U

#define BM 256
#define BN 256
#define BK 32
#define NSTEP (KTOT / BK)   // 32
#define NCHUNK 4096          // 16-row compaction chunks

typedef __attribute__((ext_vector_type(4))) unsigned int u32x4;
typedef __attribute__((ext_vector_type(4))) float f32x4;
typedef __attribute__((ext_vector_type(8))) __bf16 bf16x8;
typedef __attribute__((ext_vector_type(4))) unsigned short u16x4;

static __device__ __forceinline__ unsigned short f2bf(float f) {
    unsigned int u = __float_as_uint(f);
    u += 0x7fffu + ((u >> 16) & 1u);   // round-to-nearest-even
    return (unsigned short)(u >> 16);
}

#define GLOAD16(g, l)                                                              \
    __builtin_amdgcn_global_load_lds(                                              \
        (const __attribute__((address_space(1))) void*)(g),                        \
        (__attribute__((address_space(3))) void*)(l), 16, 0, 0)

#define VMCNT(n) asm volatile("s_waitcnt vmcnt(" #n ")" ::: "memory")
#define CFENCE   asm volatile("" ::: "memory")
#define BAR()    __builtin_amdgcn_s_barrier()

// ---- FUSED prep: validity + atomic-ticket compaction + bf16 convert +
//      invalid-row passthrough, single HBM sweep.
// Compaction order is atomic-arrival-dependent but the OUTPUT is permutation
// invariant: every valid row's GEMM result is scattered to its original
// position via cidx, so out[] is identical every call (determinism holds).
__global__ __launch_bounds__(256) void prep_fused_kernel(const int* __restrict__ adj,
                                                         const float* __restrict__ feat,
                                                         unsigned short* __restrict__ abf,
                                                         int* __restrict__ cidx,
                                                         float* __restrict__ out,
                                                         int* __restrict__ counter) {
    __shared__ int vL[16];
    __shared__ int cposL[16];
    const int c    = blockIdx.x;          // chunk of 16 rows
    const int tid  = threadIdx.x;
    const int wv   = tid >> 6;            // 0..3
    const int lane = tid & 63;

#pragma unroll
    for (int r = 0; r < 4; ++r) {
        const int li  = wv * 4 + r;
        const int row = c * 16 + li;
        const int2 a2 = reinterpret_cast<const int2*>(adj)[(size_t)row * 64 + lane];
        const int anyv = __any((a2.x >= 0) || (a2.y >= 0));
        if (lane == 0) vL[li] = anyv;
    }
    __syncthreads();

    if (tid < 64) {                        // wave 0: ticket + local prefix via ballot
        const int v = (lane < 16) ? vL[lane] : 0;
        const unsigned long long mask = __ballot(v != 0);
        const int cnt = __popcll(mask);
        int base = 0;
        if (lane == 0 && cnt) base = atomicAdd(counter, cnt);
        base = __shfl(base, 0);
        if (lane < 16) {
            const int pc = __popcll(mask & ((1ull << lane) - 1ull));
            const int cp = base + pc;
            cposL[lane] = cp;
            if (v) cidx[cp] = c * 16 + lane;
        }
    }
    __syncthreads();

#pragma unroll
    for (int r = 0; r < 4; ++r) {
        const int li  = wv * 4 + r;
        const int row = c * 16 + li;
        const f32x4* frow = reinterpret_cast<const f32x4*>(feat + (size_t)row * KTOT);
        if (vL[li]) {
            u16x4* brow = reinterpret_cast<u16x4*>(abf + (size_t)cposL[li] * KTOT);
#pragma unroll
            for (int i = 0; i < 4; ++i) {
                const f32x4 v = frow[lane + 64 * i];
                u16x4 b;
                b.x = f2bf(v[0]); b.y = f2bf(v[1]); b.z = f2bf(v[2]); b.w = f2bf(v[3]);
                brow[lane + 64 * i] = b;
            }
        } else {
            f32x4* orow = reinterpret_cast<f32x4*>(out + (size_t)row * NTOT);
#pragma unroll
            for (int i = 0; i < 4; ++i)
                orow[lane + 64 * i] = frow[lane + 64 * i];   // K==N passthrough
        }
    }
}

// ---- prep 2: kT[n][k] = bf16(kern[k][n]) ----
__global__ __launch_bounds__(256) void transposeB_kernel(const float* __restrict__ kern,
                                                         unsigned short* __restrict__ kT) {
    __shared__ float tile[32][33];
    const int bx = blockIdx.x & 31;
    const int by = blockIdx.x >> 5;
    const int tx = threadIdx.x & 31;
    const int ty = threadIdx.x >> 5;
#pragma unroll
    for (int r = 0; r < 4; ++r)
        tile[ty + r * 8][tx] = kern[(size_t)(by * 32 + ty + r * 8) * NTOT + bx * 32 + tx];
    __syncthreads();
#pragma unroll
    for (int r = 0; r < 4; ++r)
        kT[(size_t)(bx * 32 + ty + r * 8) * KTOT + by * 32 + tx] = f2bf(tile[tx][ty + r * 8]);
}

// ---- main GEMM: r13-verbatim (r7/r11 pipeline on compacted rows, XCD-interleaved
//      bm mapping so compaction-truncated tail idles all 8 XCDs equally) ----
__global__ __launch_bounds__(1024, 4) void gemm_kernel(const unsigned short* __restrict__ A,
                                                       const unsigned short* __restrict__ Bt,
                                                       const float* __restrict__ bias,
                                                       const int* __restrict__ cidx,
                                                       const int* __restrict__ nv,
                                                       float* __restrict__ out) {
    __shared__ __align__(16) unsigned short Asm[4 * 8192];
    __shared__ __align__(16) unsigned short Bsm[4 * 8192];

    const int nvalid = nv[0];

    const int tid  = threadIdx.x;
    const int lane = tid & 63;
    const int wv   = tid >> 6;
    const int wm   = wv >> 2;
    const int wn   = wv & 3;

    // xcd-interleaved bijective mapping (nwg = 1024)
    const int xcd = (int)blockIdx.x & 7;
    const int idx = (int)blockIdx.x >> 3;   // 0..127 per xcd
    const int bm  = (idx >> 2) * 8 + xcd;   // bm === xcd (mod 8); 0..255
    const int bn  = idx & 3;
    const int m0i = bm * BM;
    if (m0i >= nvalid) return;              // compacted extent; uniform exit
    const size_t m0 = (size_t)m0i;
    const int    n0 = bn * BN;

    const int srow   = tid >> 2;
    const int lch    = (tid & 3) ^ ((tid >> 3) & 3);
    const size_t s_goff = (size_t)srow * KTOT + lch * 8;
    const int    s_loff = wv << 9;

    const unsigned short* Agl = A  + m0 * (size_t)KTOT + s_goff;
    const unsigned short* Bgl = Bt + (size_t)n0 * KTOT + s_goff;

#define STAGE(b, kt) do {                                                          \
        GLOAD16(Agl + (kt) * BK, &Asm[(b) * 8192 + s_loff]);                       \
        GLOAD16(Bgl + (kt) * BK, &Bsm[(b) * 8192 + s_loff]);                       \
    } while (0)

    const int lr  = lane & 15;
    const int g4  = lane >> 4;
    const int rsw = (g4 ^ ((lr >> 1) & 3)) << 3;
    int aridx[4], bridx[4];
#pragma unroll
    for (int m = 0; m < 4; ++m)
        aridx[m] = (wm * 64 + m * 16 + lr) * BK + rsw;
#pragma unroll
    for (int n = 0; n < 4; ++n)
        bridx[n] = (wn * 64 + n * 16 + lr) * BK + rsw;

    f32x4 acc[4][4];
#pragma unroll
    for (int m = 0; m < 4; ++m)
#pragma unroll
        for (int n = 0; n < 4; ++n)
            acc[m][n] = {0.0f, 0.0f, 0.0f, 0.0f};

    STAGE(0, 0);
    STAGE(1, 1);
    STAGE(2, 2);
    VMCNT(4);
    BAR(); CFENCE;

#pragma unroll
    for (int t = 0; t < NSTEP; ++t) {
        if (t + 3 < NSTEP) STAGE((t + 3) & 3, t + 3);
        const int b = t & 3;
        bf16x8 af[4], bfr[4];
#pragma unroll
        for (int n = 0; n < 4; ++n)
            bfr[n] = __builtin_bit_cast(bf16x8, *reinterpret_cast<const u32x4*>(&Bsm[b * 8192 + bridx[n]]));
#pragma unroll
        for (int m = 0; m < 4; ++m)
            af[m] = __builtin_bit_cast(bf16x8, *reinterpret_cast<const u32x4*>(&Asm[b * 8192 + aridx[m]]));
        __builtin_amdgcn_s_setprio(1);
#pragma unroll
        for (int m = 0; m < 4; ++m)
#pragma unroll
            for (int n = 0; n < 4; ++n)
                acc[m][n] = __builtin_amdgcn_mfma_f32_16x16x32_bf16(af[m], bfr[n], acc[m][n], 0, 0, 0);
        __builtin_amdgcn_s_setprio(0);
        if (t < NSTEP - 3)       VMCNT(4);
        else if (t == NSTEP - 3) VMCNT(2);
        else if (t == NSTEP - 2) VMCNT(0);
        if (t < NSTEP - 1) { BAR(); CFENCE; }
    }

    // epilogue: compact row cr -> original row cidx[cr]; relu(acc+bias)
    float bv[4];
#pragma unroll
    for (int n = 0; n < 4; ++n)
        bv[n] = bias[n0 + wn * 64 + n * 16 + lr];

#pragma unroll
    for (int m = 0; m < 4; ++m) {
#pragma unroll
        for (int q = 0; q < 4; ++q) {
            const int cr = m0i + wm * 64 + m * 16 + g4 * 4 + q;
            if (cr < nvalid) {
                const int orow = cidx[cr];
                const size_t ro = (size_t)orow * NTOT + n0 + wn * 64 + lr;
#pragma unroll
                for (int n = 0; n < 4; ++n)
                    out[ro + n * 16] = fmaxf(acc[m][n][q] + bv[n], 0.0f);
            }
        }
    }
#undef STAGE
}

// ================= fallback (ws too small): r11 verified path =================
__global__ __launch_bounds__(256) void prep_full_kernel(const int* __restrict__ adj,
                                                        const float* __restrict__ feat,
                                                        unsigned short* __restrict__ abf,
                                                        unsigned char* __restrict__ valid,
                                                        float* __restrict__ out) {
    const int row  = blockIdx.x * 4 + (threadIdx.x >> 6);
    const int lane = threadIdx.x & 63;
    const int2 a2  = reinterpret_cast<const int2*>(adj)[(size_t)row * 64 + lane];
    const bool anyv = __any((a2.x >= 0) || (a2.y >= 0)) != 0;
    const f32x4* frow = reinterpret_cast<const f32x4*>(feat + (size_t)row * KTOT);
    u16x4*       brow = reinterpret_cast<u16x4*>(abf + (size_t)row * KTOT);
    f32x4*       orow = reinterpret_cast<f32x4*>(out + (size_t)row * NTOT);
    if (anyv) {
#pragma unroll
        for (int i = 0; i < 4; ++i) {
            const f32x4 v = frow[lane + 64 * i];
            u16x4 b;
            b.x = f2bf(v[0]); b.y = f2bf(v[1]); b.z = f2bf(v[2]); b.w = f2bf(v[3]);
            brow[lane + 64 * i] = b;
        }
    } else {
#pragma unroll
        for (int i = 0; i < 4; ++i)
            orow[lane + 64 * i] = frow[lane + 64 * i];
    }
    if (lane == 0) valid[row] = anyv ? 1 : 0;
}

__global__ __launch_bounds__(1024, 4) void gemm_full_kernel(const unsigned short* __restrict__ A,
                                                            const unsigned short* __restrict__ Bt,
                                                            const float* __restrict__ bias,
                                                            const unsigned char* __restrict__ valid,
                                                            float* __restrict__ out) {
    __shared__ __align__(16) unsigned short Asm[4 * 8192];
    __shared__ __align__(16) unsigned short Bsm[4 * 8192];
    const int tid  = threadIdx.x;
    const int lane = tid & 63;
    const int wv   = tid >> 6;
    const int wm   = wv >> 2;
    const int wn   = wv & 3;
    const int cpx = (int)gridDim.x >> 3;
    const int swz = ((int)blockIdx.x & 7) * cpx + ((int)blockIdx.x >> 3);
    const int bm  = swz >> 2;
    const int bn  = swz & 3;
    const size_t m0 = (size_t)bm * BM;
    const int    n0 = bn * BN;
    const int srow   = tid >> 2;
    const int lch    = (tid & 3) ^ ((tid >> 3) & 3);
    const size_t s_goff = (size_t)srow * KTOT + lch * 8;
    const int    s_loff = wv << 9;
    const unsigned short* Agl = A  + m0 * (size_t)KTOT + s_goff;
    const unsigned short* Bgl = Bt + (size_t)n0 * KTOT + s_goff;
#define STAGE(b, kt) do {                                                          \
        GLOAD16(Agl + (kt) * BK, &Asm[(b) * 8192 + s_loff]);                       \
        GLOAD16(Bgl + (kt) * BK, &Bsm[(b) * 8192 + s_loff]);                       \
    } while (0)
    const int lr  = lane & 15;
    const int g4  = lane >> 4;
    const int rsw = (g4 ^ ((lr >> 1) & 3)) << 3;
    int aridx[4], bridx[4];
#pragma unroll
    for (int m = 0; m < 4; ++m) aridx[m] = (wm * 64 + m * 16 + lr) * BK + rsw;
#pragma unroll
    for (int n = 0; n < 4; ++n) bridx[n] = (wn * 64 + n * 16 + lr) * BK + rsw;
    f32x4 acc[4][4];
#pragma unroll
    for (int m = 0; m < 4; ++m)
#pragma unroll
        for (int n = 0; n < 4; ++n) acc[m][n] = {0.f, 0.f, 0.f, 0.f};
    STAGE(0, 0); STAGE(1, 1); STAGE(2, 2);
    VMCNT(4); BAR(); CFENCE;
#pragma unroll
    for (int t = 0; t < NSTEP; ++t) {
        if (t + 3 < NSTEP) STAGE((t + 3) & 3, t + 3);
        const int b = t & 3;
        bf16x8 af[4], bfr[4];
#pragma unroll
        for (int n = 0; n < 4; ++n)
            bfr[n] = __builtin_bit_cast(bf16x8, *reinterpret_cast<const u32x4*>(&Bsm[b * 8192 + bridx[n]]));
#pragma unroll
        for (int m = 0; m < 4; ++m)
            af[m] = __builtin_bit_cast(bf16x8, *reinterpret_cast<const u32x4*>(&Asm[b * 8192 + aridx[m]]));
#pragma unroll
        for (int m = 0; m < 4; ++m)
#pragma unroll
            for (int n = 0; n < 4; ++n)
                acc[m][n] = __builtin_amdgcn_mfma_f32_16x16x32_bf16(af[m], bfr[n], acc[m][n], 0, 0, 0);
        if (t < NSTEP - 3)       VMCNT(4);
        else if (t == NSTEP - 3) VMCNT(2);
        else if (t == NSTEP - 2) VMCNT(0);
        if (t < NSTEP - 1) { BAR(); CFENCE; }
    }
    float bv[4];
#pragma unroll
    for (int n = 0; n < 4; ++n) bv[n] = bias[n0 + wn * 64 + n * 16 + lr];
#pragma unroll
    for (int m = 0; m < 4; ++m) {
#pragma unroll
        for (int q = 0; q < 4; ++q) {
            const size_t row = m0 + wm * 64 + m * 16 + g4 * 4 + q;
            if (valid[row]) {
                const size_t ro = row * NTOT + n0 + wn * 64 + lr;
#pragma unroll
                for (int n = 0; n < 4; ++n)
                    out[ro + n * 16] = fmaxf(acc[m][n][q] + bv[n], 0.0f);
            }
        }
    }
#undef STAGE
}

extern "C" void kernel_launch(void* const* d_in, const int* in_sizes, int n_in,
                              void* d_out, int out_size, void* d_ws, size_t ws_size,
                              hipStream_t stream) {
    const int*   adj  = (const int*)d_in[0];
    const float* feat = (const float*)d_in[1];
    const float* kern = (const float*)d_in[2];
    const float* bias = (const float*)d_in[3];
    float* out = (float*)d_out;

    char* ws = (char*)d_ws;
    unsigned short* kT    = (unsigned short*)ws;                       // 2 MB
    unsigned char*  valid = (unsigned char*)(ws + (2u << 20));         // 64 KB (fallback only)
    int*  cidx = (int*)(ws + (2u << 20) + (64u << 10));                // 256 KB
    int*  nv   = (int*)(ws + (2u << 20) + (352u << 10));               // 4 B (atomic counter)
    unsigned short* abf = (unsigned short*)(ws + (4u << 20));          // 128 MB

    const size_t need = (4ull << 20) + (size_t)MTOT * KTOT * 2;

    transposeB_kernel<<<(KTOT / 32) * (NTOT / 32), 256, 0, stream>>>(kern, kT);
    if (ws_size >= need) {
        hipMemsetAsync(nv, 0, sizeof(int), stream);
        prep_fused_kernel<<<NCHUNK, 256, 0, stream>>>(adj, feat, abf, cidx, out, nv);
        gemm_kernel<<<(MTOT / BM) * (NTOT / BN), 1024, 0, stream>>>(abf, kT, bias, cidx, nv, out);
    } else {
        unsigned short* abf_fb = (unsigned short*)(ws + (2u << 20) + (64u << 10));
        prep_full_kernel<<<MTOT / 4, 256, 0, stream>>>(adj, feat, abf_fb, valid, out);
        gemm_full_kernel<<<(MTOT / BM) * (NTOT / BN), 1024, 0, stream>>>(abf_fb, kT, bias, valid, out);
    }
}

// Round 15
// 236.914 us; speedup vs baseline: 1.0986x; 1.0986x over previous
//
#include <hip/hip_runtime.h>

#define MTOT 65536   // B*V
#define KTOT 1024    // F
#define NTOT 1024    // U

#define BM 256
#define BN 256
#define BK 32
#define NSTEP (KTOT / BK)   // 32
#define NCHUNK 4096          // 16-row compaction chunks

typedef __attribute__((ext_vector_type(4))) unsigned int u32x4;
typedef __attribute__((ext_vector_type(4))) float f32x4;
typedef __attribute__((ext_vector_type(8))) __bf16 bf16x8;
typedef __attribute__((ext_vector_type(4))) unsigned short u16x4;

static __device__ __forceinline__ unsigned short f2bf(float f) {
    unsigned int u = __float_as_uint(f);
    u += 0x7fffu + ((u >> 16) & 1u);   // round-to-nearest-even
    return (unsigned short)(u >> 16);
}

#define GLOAD16(g, l)                                                              \
    __builtin_amdgcn_global_load_lds(                                              \
        (const __attribute__((address_space(1))) void*)(g),                        \
        (__attribute__((address_space(3))) void*)(l), 16, 0, 0)

#define VMCNT(n) asm volatile("s_waitcnt vmcnt(" #n ")" ::: "memory")
#define CFENCE   asm volatile("" ::: "memory")
#define BAR()    __builtin_amdgcn_s_barrier()

// ---- stage 1 (FUSED launch): blocks [0,NCHUNK) = valid+count;
//      blocks [NCHUNK, NCHUNK+1024) = B transpose. Independent passes, one
//      dispatch: overlaps adjacency (33.5 MB) and kernel (8 MB) traffic and
//      saves a launch gap. Both consumers run strictly later (scan / gemm).
__global__ __launch_bounds__(256) void prep1_kernel(const int* __restrict__ adj,
                                                    unsigned char* __restrict__ valid,
                                                    int* __restrict__ chunkcnt,
                                                    const float* __restrict__ kern,
                                                    unsigned short* __restrict__ kT) {
    __shared__ int vb[16];
    __shared__ float tile[32][33];
    const int tid = threadIdx.x;

    if (blockIdx.x < NCHUNK) {
        // ---- valid_count body (r13-verbatim) ----
        const int c    = blockIdx.x;
        const int wv   = tid >> 6;
        const int lane = tid & 63;
#pragma unroll
        for (int r = 0; r < 4; ++r) {
            const int row = c * 16 + wv * 4 + r;
            const int2 a2 = reinterpret_cast<const int2*>(adj)[(size_t)row * 64 + lane];
            const int anyv = __any((a2.x >= 0) || (a2.y >= 0));
            if (lane == 0) { vb[wv * 4 + r] = anyv; valid[row] = (unsigned char)anyv; }
        }
        __syncthreads();
        if (tid == 0) {
            int s = 0;
#pragma unroll
            for (int i = 0; i < 16; ++i) s += vb[i];
            chunkcnt[c] = s;
        }
    } else {
        // ---- transposeB body (r13-verbatim) ----
        const int bid = blockIdx.x - NCHUNK;
        const int bx = bid & 31;
        const int by = bid >> 5;
        const int tx = tid & 31;
        const int ty = tid >> 5;
#pragma unroll
        for (int r = 0; r < 4; ++r)
            tile[ty + r * 8][tx] = kern[(size_t)(by * 32 + ty + r * 8) * NTOT + bx * 32 + tx];
        __syncthreads();
#pragma unroll
        for (int r = 0; r < 4; ++r)
            kT[(size_t)(bx * 32 + ty + r * 8) * KTOT + by * 32 + tx] = f2bf(tile[tx][ty + r * 8]);
    }
}

// ---- stage 2: exclusive scan of 4096 chunk counts -> chunkoff, nvalid ----
__global__ __launch_bounds__(1024) void scan_kernel(const int* __restrict__ chunkcnt,
                                                    int* __restrict__ chunkoff,
                                                    int* __restrict__ nv) {
    __shared__ int sc[1024];
    const int t = threadIdx.x;
    const int b = t * 4;
    const int c0 = chunkcnt[b], c1 = chunkcnt[b + 1], c2 = chunkcnt[b + 2], c3 = chunkcnt[b + 3];
    const int s = c0 + c1 + c2 + c3;
    sc[t] = s;
    __syncthreads();
    for (int d = 1; d < 1024; d <<= 1) {
        const int v = (t >= d) ? sc[t - d] : 0;
        __syncthreads();
        sc[t] += v;
        __syncthreads();
    }
    const int excl = sc[t] - s;
    chunkoff[b]     = excl;
    chunkoff[b + 1] = excl + c0;
    chunkoff[b + 2] = excl + c0 + c1;
    chunkoff[b + 3] = excl + c0 + c1 + c2;
    if (t == 1023) nv[0] = sc[t];
}

// ---- stage 3: compacting prep (r13-verbatim): bf16-convert valid rows densely
//      into abf (SORTED order -> GEMM epilogue writes stay spatially local),
//      record cidx, passthrough invalid rows to out (K==N) ----
__global__ __launch_bounds__(256) void prep_compact_kernel(const unsigned char* __restrict__ valid,
                                                           const int* __restrict__ chunkoff,
                                                           const float* __restrict__ feat,
                                                           unsigned short* __restrict__ abf,
                                                           int* __restrict__ cidx,
                                                           float* __restrict__ out) {
    __shared__ int cposL[16];
    __shared__ int vL[16];
    const int c    = blockIdx.x;          // chunk of 16 rows
    const int tid  = threadIdx.x;
    const int wv   = tid >> 6;
    const int lane = tid & 63;

    if (tid < 64) {                        // wave 0: local prefix via ballot
        const int v = (lane < 16) ? (int)valid[c * 16 + lane] : 0;
        const unsigned long long mask = __ballot(v != 0);
        if (lane < 16) {
            const int pc = __popcll(mask & ((1ull << lane) - 1ull));
            const int cp = chunkoff[c] + pc;
            cposL[lane] = cp;
            vL[lane]    = v;
            if (v) cidx[cp] = c * 16 + lane;
        }
    }
    __syncthreads();

#pragma unroll
    for (int r = 0; r < 4; ++r) {
        const int li  = wv * 4 + r;
        const int row = c * 16 + li;
        const f32x4* frow = reinterpret_cast<const f32x4*>(feat + (size_t)row * KTOT);
        if (vL[li]) {
            u16x4* brow = reinterpret_cast<u16x4*>(abf + (size_t)cposL[li] * KTOT);
#pragma unroll
            for (int i = 0; i < 4; ++i) {
                const f32x4 v = frow[lane + 64 * i];
                u16x4 b;
                b.x = f2bf(v[0]); b.y = f2bf(v[1]); b.z = f2bf(v[2]); b.w = f2bf(v[3]);
                brow[lane + 64 * i] = b;
            }
        } else {
            f32x4* orow = reinterpret_cast<f32x4*>(out + (size_t)row * NTOT);
#pragma unroll
            for (int i = 0; i < 4; ++i)
                orow[lane + 64 * i] = frow[lane + 64 * i];
        }
    }
}

// ---- main GEMM: r13-verbatim (r7/r11 pipeline on compacted rows,
//      XCD-interleaved bm mapping: bm === xcd (mod 8) so the compaction-
//      truncated tail idles all 8 XCDs equally) ----
__global__ __launch_bounds__(1024, 4) void gemm_kernel(const unsigned short* __restrict__ A,
                                                       const unsigned short* __restrict__ Bt,
                                                       const float* __restrict__ bias,
                                                       const int* __restrict__ cidx,
                                                       const int* __restrict__ nv,
                                                       float* __restrict__ out) {
    __shared__ __align__(16) unsigned short Asm[4 * 8192];
    __shared__ __align__(16) unsigned short Bsm[4 * 8192];

    const int nvalid = nv[0];

    const int tid  = threadIdx.x;
    const int lane = tid & 63;
    const int wv   = tid >> 6;
    const int wm   = wv >> 2;
    const int wn   = wv & 3;

    // xcd-interleaved bijective mapping (nwg = 1024)
    const int xcd = (int)blockIdx.x & 7;
    const int idx = (int)blockIdx.x >> 3;   // 0..127 per xcd
    const int bm  = (idx >> 2) * 8 + xcd;   // bm === xcd (mod 8); 0..255
    const int bn  = idx & 3;
    const int m0i = bm * BM;
    if (m0i >= nvalid) return;              // compacted extent; uniform exit
    const size_t m0 = (size_t)m0i;
    const int    n0 = bn * BN;

    const int srow   = tid >> 2;
    const int lch    = (tid & 3) ^ ((tid >> 3) & 3);
    const size_t s_goff = (size_t)srow * KTOT + lch * 8;
    const int    s_loff = wv << 9;

    const unsigned short* Agl = A  + m0 * (size_t)KTOT + s_goff;
    const unsigned short* Bgl = Bt + (size_t)n0 * KTOT + s_goff;

#define STAGE(b, kt) do {                                                          \
        GLOAD16(Agl + (kt) * BK, &Asm[(b) * 8192 + s_loff]);                       \
        GLOAD16(Bgl + (kt) * BK, &Bsm[(b) * 8192 + s_loff]);                       \
    } while (0)

    const int lr  = lane & 15;
    const int g4  = lane >> 4;
    const int rsw = (g4 ^ ((lr >> 1) & 3)) << 3;
    int aridx[4], bridx[4];
#pragma unroll
    for (int m = 0; m < 4; ++m)
        aridx[m] = (wm * 64 + m * 16 + lr) * BK + rsw;
#pragma unroll
    for (int n = 0; n < 4; ++n)
        bridx[n] = (wn * 64 + n * 16 + lr) * BK + rsw;

    f32x4 acc[4][4];
#pragma unroll
    for (int m = 0; m < 4; ++m)
#pragma unroll
        for (int n = 0; n < 4; ++n)
            acc[m][n] = {0.0f, 0.0f, 0.0f, 0.0f};

    STAGE(0, 0);
    STAGE(1, 1);
    STAGE(2, 2);
    VMCNT(4);
    BAR(); CFENCE;

#pragma unroll
    for (int t = 0; t < NSTEP; ++t) {
        if (t + 3 < NSTEP) STAGE((t + 3) & 3, t + 3);
        const int b = t & 3;
        bf16x8 af[4], bfr[4];
#pragma unroll
        for (int n = 0; n < 4; ++n)
            bfr[n] = __builtin_bit_cast(bf16x8, *reinterpret_cast<const u32x4*>(&Bsm[b * 8192 + bridx[n]]));
#pragma unroll
        for (int m = 0; m < 4; ++m)
            af[m] = __builtin_bit_cast(bf16x8, *reinterpret_cast<const u32x4*>(&Asm[b * 8192 + aridx[m]]));
        __builtin_amdgcn_s_setprio(1);
#pragma unroll
        for (int m = 0; m < 4; ++m)
#pragma unroll
            for (int n = 0; n < 4; ++n)
                acc[m][n] = __builtin_amdgcn_mfma_f32_16x16x32_bf16(af[m], bfr[n], acc[m][n], 0, 0, 0);
        __builtin_amdgcn_s_setprio(0);
        if (t < NSTEP - 3)       VMCNT(4);
        else if (t == NSTEP - 3) VMCNT(2);
        else if (t == NSTEP - 2) VMCNT(0);
        if (t < NSTEP - 1) { BAR(); CFENCE; }
    }

    // epilogue: compact row cr -> original row cidx[cr]; relu(acc+bias)
    float bv[4];
#pragma unroll
    for (int n = 0; n < 4; ++n)
        bv[n] = bias[n0 + wn * 64 + n * 16 + lr];

#pragma unroll
    for (int m = 0; m < 4; ++m) {
#pragma unroll
        for (int q = 0; q < 4; ++q) {
            const int cr = m0i + wm * 64 + m * 16 + g4 * 4 + q;
            if (cr < nvalid) {
                const int orow = cidx[cr];
                const size_t ro = (size_t)orow * NTOT + n0 + wn * 64 + lr;
#pragma unroll
                for (int n = 0; n < 4; ++n)
                    out[ro + n * 16] = fmaxf(acc[m][n][q] + bv[n], 0.0f);
            }
        }
    }
#undef STAGE
}

// ================= fallback (ws too small): r11 verified path =================
__global__ __launch_bounds__(256) void prep_full_kernel(const int* __restrict__ adj,
                                                        const float* __restrict__ feat,
                                                        unsigned short* __restrict__ abf,
                                                        unsigned char* __restrict__ valid,
                                                        float* __restrict__ out) {
    const int row  = blockIdx.x * 4 + (threadIdx.x >> 6);
    const int lane = threadIdx.x & 63;
    const int2 a2  = reinterpret_cast<const int2*>(adj)[(size_t)row * 64 + lane];
    const bool anyv = __any((a2.x >= 0) || (a2.y >= 0)) != 0;
    const f32x4* frow = reinterpret_cast<const f32x4*>(feat + (size_t)row * KTOT);
    u16x4*       brow = reinterpret_cast<u16x4*>(abf + (size_t)row * KTOT);
    f32x4*       orow = reinterpret_cast<f32x4*>(out + (size_t)row * NTOT);
    if (anyv) {
#pragma unroll
        for (int i = 0; i < 4; ++i) {
            const f32x4 v = frow[lane + 64 * i];
            u16x4 b;
            b.x = f2bf(v[0]); b.y = f2bf(v[1]); b.z = f2bf(v[2]); b.w = f2bf(v[3]);
            brow[lane + 64 * i] = b;
        }
    } else {
#pragma unroll
        for (int i = 0; i < 4; ++i)
            orow[lane + 64 * i] = frow[lane + 64 * i];
    }
    if (lane == 0) valid[row] = anyv ? 1 : 0;
}

__global__ __launch_bounds__(256) void transposeB_kernel(const float* __restrict__ kern,
                                                         unsigned short* __restrict__ kT) {
    __shared__ float tile[32][33];
    const int bx = blockIdx.x & 31;
    const int by = blockIdx.x >> 5;
    const int tx = threadIdx.x & 31;
    const int ty = threadIdx.x >> 5;
#pragma unroll
    for (int r = 0; r < 4; ++r)
        tile[ty + r * 8][tx] = kern[(size_t)(by * 32 + ty + r * 8) * NTOT + bx * 32 + tx];
    __syncthreads();
#pragma unroll
    for (int r = 0; r < 4; ++r)
        kT[(size_t)(bx * 32 + ty + r * 8) * KTOT + by * 32 + tx] = f2bf(tile[tx][ty + r * 8]);
}

__global__ __launch_bounds__(1024, 4) void gemm_full_kernel(const unsigned short* __restrict__ A,
                                                            const unsigned short* __restrict__ Bt,
                                                            const float* __restrict__ bias,
                                                            const unsigned char* __restrict__ valid,
                                                            float* __restrict__ out) {
    __shared__ __align__(16) unsigned short Asm[4 * 8192];
    __shared__ __align__(16) unsigned short Bsm[4 * 8192];
    const int tid  = threadIdx.x;
    const int lane = tid & 63;
    const int wv   = tid >> 6;
    const int wm   = wv >> 2;
    const int wn   = wv & 3;
    const int cpx = (int)gridDim.x >> 3;
    const int swz = ((int)blockIdx.x & 7) * cpx + ((int)blockIdx.x >> 3);
    const int bm  = swz >> 2;
    const int bn  = swz & 3;
    const size_t m0 = (size_t)bm * BM;
    const int    n0 = bn * BN;
    const int srow   = tid >> 2;
    const int lch    = (tid & 3) ^ ((tid >> 3) & 3);
    const size_t s_goff = (size_t)srow * KTOT + lch * 8;
    const int    s_loff = wv << 9;
    const unsigned short* Agl = A  + m0 * (size_t)KTOT + s_goff;
    const unsigned short* Bgl = Bt + (size_t)n0 * KTOT + s_goff;
#define STAGE(b, kt) do {                                                          \
        GLOAD16(Agl + (kt) * BK, &Asm[(b) * 8192 + s_loff]);                       \
        GLOAD16(Bgl + (kt) * BK, &Bsm[(b) * 8192 + s_loff]);                       \
    } while (0)
    const int lr  = lane & 15;
    const int g4  = lane >> 4;
    const int rsw = (g4 ^ ((lr >> 1) & 3)) << 3;
    int aridx[4], bridx[4];
#pragma unroll
    for (int m = 0; m < 4; ++m) aridx[m] = (wm * 64 + m * 16 + lr) * BK + rsw;
#pragma unroll
    for (int n = 0; n < 4; ++n) bridx[n] = (wn * 64 + n * 16 + lr) * BK + rsw;
    f32x4 acc[4][4];
#pragma unroll
    for (int m = 0; m < 4; ++m)
#pragma unroll
        for (int n = 0; n < 4; ++n) acc[m][n] = {0.f, 0.f, 0.f, 0.f};
    STAGE(0, 0); STAGE(1, 1); STAGE(2, 2);
    VMCNT(4); BAR(); CFENCE;
#pragma unroll
    for (int t = 0; t < NSTEP; ++t) {
        if (t + 3 < NSTEP) STAGE((t + 3) & 3, t + 3);
        const int b = t & 3;
        bf16x8 af[4], bfr[4];
#pragma unroll
        for (int n = 0; n < 4; ++n)
            bfr[n] = __builtin_bit_cast(bf16x8, *reinterpret_cast<const u32x4*>(&Bsm[b * 8192 + bridx[n]]));
#pragma unroll
        for (int m = 0; m < 4; ++m)
            af[m] = __builtin_bit_cast(bf16x8, *reinterpret_cast<const u32x4*>(&Asm[b * 8192 + aridx[m]]));
#pragma unroll
        for (int m = 0; m < 4; ++m)
#pragma unroll
            for (int n = 0; n < 4; ++n)
                acc[m][n] = __builtin_amdgcn_mfma_f32_16x16x32_bf16(af[m], bfr[n], acc[m][n], 0, 0, 0);
        if (t < NSTEP - 3)       VMCNT(4);
        else if (t == NSTEP - 3) VMCNT(2);
        else if (t == NSTEP - 2) VMCNT(0);
        if (t < NSTEP - 1) { BAR(); CFENCE; }
    }
    float bv[4];
#pragma unroll
    for (int n = 0; n < 4; ++n) bv[n] = bias[n0 + wn * 64 + n * 16 + lr];
#pragma unroll
    for (int m = 0; m < 4; ++m) {
#pragma unroll
        for (int q = 0; q < 4; ++q) {
            const size_t row = m0 + wm * 64 + m * 16 + g4 * 4 + q;
            if (valid[row]) {
                const size_t ro = row * NTOT + n0 + wn * 64 + lr;
#pragma unroll
                for (int n = 0; n < 4; ++n)
                    out[ro + n * 16] = fmaxf(acc[m][n][q] + bv[n], 0.0f);
            }
        }
    }
#undef STAGE
}

extern "C" void kernel_launch(void* const* d_in, const int* in_sizes, int n_in,
                              void* d_out, int out_size, void* d_ws, size_t ws_size,
                              hipStream_t stream) {
    const int*   adj  = (const int*)d_in[0];
    const float* feat = (const float*)d_in[1];
    const float* kern = (const float*)d_in[2];
    const float* bias = (const float*)d_in[3];
    float* out = (float*)d_out;

    char* ws = (char*)d_ws;
    unsigned short* kT    = (unsigned short*)ws;                       // 2 MB
    unsigned char*  valid = (unsigned char*)(ws + (2u << 20));         // 64 KB
    int*  cidx     = (int*)(ws + (2u << 20) + (64u << 10));            // 256 KB
    int*  chunkcnt = (int*)(ws + (2u << 20) + (320u << 10));           // 16 KB
    int*  chunkoff = (int*)(ws + (2u << 20) + (336u << 10));           // 16 KB
    int*  nv       = (int*)(ws + (2u << 20) + (352u << 10));           // 16 B
    unsigned short* abf = (unsigned short*)(ws + (4u << 20));          // 128 MB

    const size_t need = (4ull << 20) + (size_t)MTOT * KTOT * 2;

    if (ws_size >= need) {
        prep1_kernel<<<NCHUNK + (KTOT / 32) * (NTOT / 32), 256, 0, stream>>>(adj, valid, chunkcnt, kern, kT);
        scan_kernel<<<1, 1024, 0, stream>>>(chunkcnt, chunkoff, nv);
        prep_compact_kernel<<<NCHUNK, 256, 0, stream>>>(valid, chunkoff, feat, abf, cidx, out);
        gemm_kernel<<<(MTOT / BM) * (NTOT / BN), 1024, 0, stream>>>(abf, kT, bias, cidx, nv, out);
    } else {
        transposeB_kernel<<<(KTOT / 32) * (NTOT / 32), 256, 0, stream>>>(kern, kT);
        unsigned short* abf_fb = (unsigned short*)(ws + (2u << 20) + (64u << 10));
        prep_full_kernel<<<MTOT / 4, 256, 0, stream>>>(adj, feat, abf_fb, valid, out);
        gemm_full_kernel<<<(MTOT / BM) * (NTOT / BN), 1024, 0, stream>>>(abf_fb, kT, bias, valid, out);
    }
}

// Round 17
// 210.510 us; speedup vs baseline: 1.2364x; 1.1254x over previous
//
#include <hip/hip_runtime.h>

#define MTOT 65536   // B*V
#define KTOT 1024    // F
#define NTOT 1024    // U

#define BM 256
#define BN 256
#define BK 32
#define NSTEP (KTOT / BK)   // 32
#define NCHUNK 4096          // 16-row compaction chunks

typedef __attribute__((ext_vector_type(4))) unsigned int u32x4;
typedef __attribute__((ext_vector_type(4))) float f32x4;
typedef __attribute__((ext_vector_type(8))) __bf16 bf16x8;
typedef __attribute__((ext_vector_type(4))) unsigned short u16x4;

static __device__ __forceinline__ unsigned short f2bf(float f) {
    unsigned int u = __float_as_uint(f);
    u += 0x7fffu + ((u >> 16) & 1u);   // round-to-nearest-even
    return (unsigned short)(u >> 16);
}

#define GLOAD16(g, l)                                                              \
    __builtin_amdgcn_global_load_lds(                                              \
        (const __attribute__((address_space(1))) void*)(g),                        \
        (__attribute__((address_space(3))) void*)(l), 16, 0, 0)

#define VMCNT(n) asm volatile("s_waitcnt vmcnt(" #n ")" ::: "memory")
#define CFENCE   asm volatile("" ::: "memory")
#define BAR()    __builtin_amdgcn_s_barrier()

// ---- stage 1 (FUSED launch): blocks [0,NCHUNK) = valid+count;
//      blocks [NCHUNK, NCHUNK+1024) = B transpose. ----
__global__ __launch_bounds__(256) void prep1_kernel(const int* __restrict__ adj,
                                                    unsigned char* __restrict__ valid,
                                                    int* __restrict__ chunkcnt,
                                                    const float* __restrict__ kern,
                                                    unsigned short* __restrict__ kT) {
    __shared__ int vb[16];
    __shared__ float tile[32][33];
    const int tid = threadIdx.x;

    if (blockIdx.x < NCHUNK) {
        const int c    = blockIdx.x;
        const int wv   = tid >> 6;
        const int lane = tid & 63;
#pragma unroll
        for (int r = 0; r < 4; ++r) {
            const int row = c * 16 + wv * 4 + r;
            // adjacency read exactly once -> nontemporal (as u64; int2 is a
            // class type the builtin rejects). valid iff either int's sign bit
            // is clear.
            const unsigned long long a2u = __builtin_nontemporal_load(
                reinterpret_cast<const unsigned long long*>(adj) + (size_t)row * 64 + lane);
            const int anyv = __any((a2u & 0x8000000080000000ull) != 0x8000000080000000ull);
            if (lane == 0) { vb[wv * 4 + r] = anyv; valid[row] = (unsigned char)anyv; }
        }
        __syncthreads();
        if (tid == 0) {
            int s = 0;
#pragma unroll
            for (int i = 0; i < 16; ++i) s += vb[i];
            chunkcnt[c] = s;
        }
    } else {
        const int bid = blockIdx.x - NCHUNK;
        const int bx = bid & 31;
        const int by = bid >> 5;
        const int tx = tid & 31;
        const int ty = tid >> 5;
#pragma unroll
        for (int r = 0; r < 4; ++r)
            tile[ty + r * 8][tx] = kern[(size_t)(by * 32 + ty + r * 8) * NTOT + bx * 32 + tx];
        __syncthreads();
#pragma unroll
        for (int r = 0; r < 4; ++r)
            kT[(size_t)(bx * 32 + ty + r * 8) * KTOT + by * 32 + tx] = f2bf(tile[tx][ty + r * 8]);
    }
}

// ---- stage 2: exclusive scan of 4096 chunk counts -> chunkoff, nvalid ----
__global__ __launch_bounds__(1024) void scan_kernel(const int* __restrict__ chunkcnt,
                                                    int* __restrict__ chunkoff,
                                                    int* __restrict__ nv) {
    __shared__ int sc[1024];
    const int t = threadIdx.x;
    const int b = t * 4;
    const int c0 = chunkcnt[b], c1 = chunkcnt[b + 1], c2 = chunkcnt[b + 2], c3 = chunkcnt[b + 3];
    const int s = c0 + c1 + c2 + c3;
    sc[t] = s;
    __syncthreads();
    for (int d = 1; d < 1024; d <<= 1) {
        const int v = (t >= d) ? sc[t - d] : 0;
        __syncthreads();
        sc[t] += v;
        __syncthreads();
    }
    const int excl = sc[t] - s;
    chunkoff[b]     = excl;
    chunkoff[b + 1] = excl + c0;
    chunkoff[b + 2] = excl + c0 + c1;
    chunkoff[b + 3] = excl + c0 + c1 + c2;
    if (t == 1023) nv[0] = sc[t];
}

// ---- stage 3: compacting prep (sorted order -> spatially local epilogue writes):
//      bf16-convert valid rows densely into abf, record cidx, passthrough
//      invalid rows to out. feat read-once -> NT loads; out never re-read -> NT
//      stores; abf re-read by gemm -> normal (cached) stores. ----
__global__ __launch_bounds__(256) void prep_compact_kernel(const unsigned char* __restrict__ valid,
                                                           const int* __restrict__ chunkoff,
                                                           const float* __restrict__ feat,
                                                           unsigned short* __restrict__ abf,
                                                           int* __restrict__ cidx,
                                                           float* __restrict__ out) {
    __shared__ int cposL[16];
    __shared__ int vL[16];
    const int c    = blockIdx.x;          // chunk of 16 rows
    const int tid  = threadIdx.x;
    const int wv   = tid >> 6;
    const int lane = tid & 63;

    if (tid < 64) {                        // wave 0: local prefix via ballot
        const int v = (lane < 16) ? (int)valid[c * 16 + lane] : 0;
        const unsigned long long mask = __ballot(v != 0);
        if (lane < 16) {
            const int pc = __popcll(mask & ((1ull << lane) - 1ull));
            const int cp = chunkoff[c] + pc;
            cposL[lane] = cp;
            vL[lane]    = v;
            if (v) cidx[cp] = c * 16 + lane;
        }
    }
    __syncthreads();

#pragma unroll
    for (int r = 0; r < 4; ++r) {
        const int li  = wv * 4 + r;
        const int row = c * 16 + li;
        const f32x4* frow = reinterpret_cast<const f32x4*>(feat + (size_t)row * KTOT);
        if (vL[li]) {
            u16x4* brow = reinterpret_cast<u16x4*>(abf + (size_t)cposL[li] * KTOT);
#pragma unroll
            for (int i = 0; i < 4; ++i) {
                const f32x4 v = __builtin_nontemporal_load(&frow[lane + 64 * i]);
                u16x4 b;
                b.x = f2bf(v[0]); b.y = f2bf(v[1]); b.z = f2bf(v[2]); b.w = f2bf(v[3]);
                brow[lane + 64 * i] = b;
            }
        } else {
            f32x4* orow = reinterpret_cast<f32x4*>(out + (size_t)row * NTOT);
#pragma unroll
            for (int i = 0; i < 4; ++i) {
                const f32x4 v = __builtin_nontemporal_load(&frow[lane + 64 * i]);
                __builtin_nontemporal_store(v, &orow[lane + 64 * i]);
            }
        }
    }
}

// ---- main GEMM: r13/r15-verbatim pipeline on compacted rows; epilogue stores
//      nontemporal (output never re-read -> no L2 write-allocate pressure on
//      the A/B panels). XCD-interleaved bm mapping: bm === xcd (mod 8). ----
__global__ __launch_bounds__(1024, 4) void gemm_kernel(const unsigned short* __restrict__ A,
                                                       const unsigned short* __restrict__ Bt,
                                                       const float* __restrict__ bias,
                                                       const int* __restrict__ cidx,
                                                       const int* __restrict__ nv,
                                                       float* __restrict__ out) {
    __shared__ __align__(16) unsigned short Asm[4 * 8192];
    __shared__ __align__(16) unsigned short Bsm[4 * 8192];

    const int nvalid = nv[0];

    const int tid  = threadIdx.x;
    const int lane = tid & 63;
    const int wv   = tid >> 6;
    const int wm   = wv >> 2;
    const int wn   = wv & 3;

    // xcd-interleaved bijective mapping (nwg = 1024)
    const int xcd = (int)blockIdx.x & 7;
    const int idx = (int)blockIdx.x >> 3;   // 0..127 per xcd
    const int bm  = (idx >> 2) * 8 + xcd;   // bm === xcd (mod 8); 0..255
    const int bn  = idx & 3;
    const int m0i = bm * BM;
    if (m0i >= nvalid) return;              // compacted extent; uniform exit
    const size_t m0 = (size_t)m0i;
    const int    n0 = bn * BN;

    const int srow   = tid >> 2;
    const int lch    = (tid & 3) ^ ((tid >> 3) & 3);
    const size_t s_goff = (size_t)srow * KTOT + lch * 8;
    const int    s_loff = wv << 9;

    const unsigned short* Agl = A  + m0 * (size_t)KTOT + s_goff;
    const unsigned short* Bgl = Bt + (size_t)n0 * KTOT + s_goff;

#define STAGE(b, kt) do {                                                          \
        GLOAD16(Agl + (kt) * BK, &Asm[(b) * 8192 + s_loff]);                       \
        GLOAD16(Bgl + (kt) * BK, &Bsm[(b) * 8192 + s_loff]);                       \
    } while (0)

    const int lr  = lane & 15;
    const int g4  = lane >> 4;
    const int rsw = (g4 ^ ((lr >> 1) & 3)) << 3;
    int aridx[4], bridx[4];
#pragma unroll
    for (int m = 0; m < 4; ++m)
        aridx[m] = (wm * 64 + m * 16 + lr) * BK + rsw;
#pragma unroll
    for (int n = 0; n < 4; ++n)
        bridx[n] = (wn * 64 + n * 16 + lr) * BK + rsw;

    f32x4 acc[4][4];
#pragma unroll
    for (int m = 0; m < 4; ++m)
#pragma unroll
        for (int n = 0; n < 4; ++n)
            acc[m][n] = {0.0f, 0.0f, 0.0f, 0.0f};

    STAGE(0, 0);
    STAGE(1, 1);
    STAGE(2, 2);
    VMCNT(4);
    BAR(); CFENCE;

#pragma unroll
    for (int t = 0; t < NSTEP; ++t) {
        if (t + 3 < NSTEP) STAGE((t + 3) & 3, t + 3);
        const int b = t & 3;
        bf16x8 af[4], bfr[4];
#pragma unroll
        for (int n = 0; n < 4; ++n)
            bfr[n] = __builtin_bit_cast(bf16x8, *reinterpret_cast<const u32x4*>(&Bsm[b * 8192 + bridx[n]]));
#pragma unroll
        for (int m = 0; m < 4; ++m)
            af[m] = __builtin_bit_cast(bf16x8, *reinterpret_cast<const u32x4*>(&Asm[b * 8192 + aridx[m]]));
        __builtin_amdgcn_s_setprio(1);
#pragma unroll
        for (int m = 0; m < 4; ++m)
#pragma unroll
            for (int n = 0; n < 4; ++n)
                acc[m][n] = __builtin_amdgcn_mfma_f32_16x16x32_bf16(af[m], bfr[n], acc[m][n], 0, 0, 0);
        __builtin_amdgcn_s_setprio(0);
        if (t < NSTEP - 3)       VMCNT(4);
        else if (t == NSTEP - 3) VMCNT(2);
        else if (t == NSTEP - 2) VMCNT(0);
        if (t < NSTEP - 1) { BAR(); CFENCE; }
    }

    // epilogue: compact row cr -> original row cidx[cr]; relu(acc+bias); NT stores
    float bv[4];
#pragma unroll
    for (int n = 0; n < 4; ++n)
        bv[n] = bias[n0 + wn * 64 + n * 16 + lr];

#pragma unroll
    for (int m = 0; m < 4; ++m) {
#pragma unroll
        for (int q = 0; q < 4; ++q) {
            const int cr = m0i + wm * 64 + m * 16 + g4 * 4 + q;
            if (cr < nvalid) {
                const int orow = cidx[cr];
                const size_t ro = (size_t)orow * NTOT + n0 + wn * 64 + lr;
#pragma unroll
                for (int n = 0; n < 4; ++n)
                    __builtin_nontemporal_store(fmaxf(acc[m][n][q] + bv[n], 0.0f),
                                                &out[ro + n * 16]);
            }
        }
    }
#undef STAGE
}

// ================= fallback (ws too small): r11 verified path =================
__global__ __launch_bounds__(256) void prep_full_kernel(const int* __restrict__ adj,
                                                        const float* __restrict__ feat,
                                                        unsigned short* __restrict__ abf,
                                                        unsigned char* __restrict__ valid,
                                                        float* __restrict__ out) {
    const int row  = blockIdx.x * 4 + (threadIdx.x >> 6);
    const int lane = threadIdx.x & 63;
    const int2 a2  = reinterpret_cast<const int2*>(adj)[(size_t)row * 64 + lane];
    const bool anyv = __any((a2.x >= 0) || (a2.y >= 0)) != 0;
    const f32x4* frow = reinterpret_cast<const f32x4*>(feat + (size_t)row * KTOT);
    u16x4*       brow = reinterpret_cast<u16x4*>(abf + (size_t)row * KTOT);
    f32x4*       orow = reinterpret_cast<f32x4*>(out + (size_t)row * NTOT);
    if (anyv) {
#pragma unroll
        for (int i = 0; i < 4; ++i) {
            const f32x4 v = frow[lane + 64 * i];
            u16x4 b;
            b.x = f2bf(v[0]); b.y = f2bf(v[1]); b.z = f2bf(v[2]); b.w = f2bf(v[3]);
            brow[lane + 64 * i] = b;
        }
    } else {
#pragma unroll
        for (int i = 0; i < 4; ++i)
            orow[lane + 64 * i] = frow[lane + 64 * i];
    }
    if (lane == 0) valid[row] = anyv ? 1 : 0;
}

__global__ __launch_bounds__(256) void transposeB_kernel(const float* __restrict__ kern,
                                                         unsigned short* __restrict__ kT) {
    __shared__ float tile[32][33];
    const int bx = blockIdx.x & 31;
    const int by = blockIdx.x >> 5;
    const int tx = threadIdx.x & 31;
    const int ty = threadIdx.x >> 5;
#pragma unroll
    for (int r = 0; r < 4; ++r)
        tile[ty + r * 8][tx] = kern[(size_t)(by * 32 + ty + r * 8) * NTOT + bx * 32 + tx];
    __syncthreads();
#pragma unroll
    for (int r = 0; r < 4; ++r)
        kT[(size_t)(bx * 32 + ty + r * 8) * KTOT + by * 32 + tx] = f2bf(tile[tx][ty + r * 8]);
}

__global__ __launch_bounds__(1024, 4) void gemm_full_kernel(const unsigned short* __restrict__ A,
                                                            const unsigned short* __restrict__ Bt,
                                                            const float* __restrict__ bias,
                                                            const unsigned char* __restrict__ valid,
                                                            float* __restrict__ out) {
    __shared__ __align__(16) unsigned short Asm[4 * 8192];
    __shared__ __align__(16) unsigned short Bsm[4 * 8192];
    const int tid  = threadIdx.x;
    const int lane = tid & 63;
    const int wv   = tid >> 6;
    const int wm   = wv >> 2;
    const int wn   = wv & 3;
    const int cpx = (int)gridDim.x >> 3;
    const int swz = ((int)blockIdx.x & 7) * cpx + ((int)blockIdx.x >> 3);
    const int bm  = swz >> 2;
    const int bn  = swz & 3;
    const size_t m0 = (size_t)bm * BM;
    const int    n0 = bn * BN;
    const int srow   = tid >> 2;
    const int lch    = (tid & 3) ^ ((tid >> 3) & 3);
    const size_t s_goff = (size_t)srow * KTOT + lch * 8;
    const int    s_loff = wv << 9;
    const unsigned short* Agl = A  + m0 * (size_t)KTOT + s_goff;
    const unsigned short* Bgl = Bt + (size_t)n0 * KTOT + s_goff;
#define STAGE(b, kt) do {                                                          \
        GLOAD16(Agl + (kt) * BK, &Asm[(b) * 8192 + s_loff]);                       \
        GLOAD16(Bgl + (kt) * BK, &Bsm[(b) * 8192 + s_loff]);                       \
    } while (0)
    const int lr  = lane & 15;
    const int g4  = lane >> 4;
    const int rsw = (g4 ^ ((lr >> 1) & 3)) << 3;
    int aridx[4], bridx[4];
#pragma unroll
    for (int m = 0; m < 4; ++m) aridx[m] = (wm * 64 + m * 16 + lr) * BK + rsw;
#pragma unroll
    for (int n = 0; n < 4; ++n) bridx[n] = (wn * 64 + n * 16 + lr) * BK + rsw;
    f32x4 acc[4][4];
#pragma unroll
    for (int m = 0; m < 4; ++m)
#pragma unroll
        for (int n = 0; n < 4; ++n) acc[m][n] = {0.f, 0.f, 0.f, 0.f};
    STAGE(0, 0); STAGE(1, 1); STAGE(2, 2);
    VMCNT(4); BAR(); CFENCE;
#pragma unroll
    for (int t = 0; t < NSTEP; ++t) {
        if (t + 3 < NSTEP) STAGE((t + 3) & 3, t + 3);
        const int b = t & 3;
        bf16x8 af[4], bfr[4];
#pragma unroll
        for (int n = 0; n < 4; ++n)
            bfr[n] = __builtin_bit_cast(bf16x8, *reinterpret_cast<const u32x4*>(&Bsm[b * 8192 + bridx[n]]));
#pragma unroll
        for (int m = 0; m < 4; ++m)
            af[m] = __builtin_bit_cast(bf16x8, *reinterpret_cast<const u32x4*>(&Asm[b * 8192 + aridx[m]]));
#pragma unroll
        for (int m = 0; m < 4; ++m)
#pragma unroll
            for (int n = 0; n < 4; ++n)
                acc[m][n] = __builtin_amdgcn_mfma_f32_16x16x32_bf16(af[m], bfr[n], acc[m][n], 0, 0, 0);
        if (t < NSTEP - 3)       VMCNT(4);
        else if (t == NSTEP - 3) VMCNT(2);
        else if (t == NSTEP - 2) VMCNT(0);
        if (t < NSTEP - 1) { BAR(); CFENCE; }
    }
    float bv[4];
#pragma unroll
    for (int n = 0; n < 4; ++n) bv[n] = bias[n0 + wn * 64 + n * 16 + lr];
#pragma unroll
    for (int m = 0; m < 4; ++m) {
#pragma unroll
        for (int q = 0; q < 4; ++q) {
            const size_t row = m0 + wm * 64 + m * 16 + g4 * 4 + q;
            if (valid[row]) {
                const size_t ro = row * NTOT + n0 + wn * 64 + lr;
#pragma unroll
                for (int n = 0; n < 4; ++n)
                    out[ro + n * 16] = fmaxf(acc[m][n][q] + bv[n], 0.0f);
            }
        }
    }
#undef STAGE
}

extern "C" void kernel_launch(void* const* d_in, const int* in_sizes, int n_in,
                              void* d_out, int out_size, void* d_ws, size_t ws_size,
                              hipStream_t stream) {
    const int*   adj  = (const int*)d_in[0];
    const float* feat = (const float*)d_in[1];
    const float* kern = (const float*)d_in[2];
    const float* bias = (const float*)d_in[3];
    float* out = (float*)d_out;

    char* ws = (char*)d_ws;
    unsigned short* kT    = (unsigned short*)ws;                       // 2 MB
    unsigned char*  valid = (unsigned char*)(ws + (2u << 20));         // 64 KB
    int*  cidx     = (int*)(ws + (2u << 20) + (64u << 10));            // 256 KB
    int*  chunkcnt = (int*)(ws + (2u << 20) + (320u << 10));           // 16 KB
    int*  chunkoff = (int*)(ws + (2u << 20) + (336u << 10));           // 16 KB
    int*  nv       = (int*)(ws + (2u << 20) + (352u << 10));           // 16 B
    unsigned short* abf = (unsigned short*)(ws + (4u << 20));          // 128 MB

    const size_t need = (4ull << 20) + (size_t)MTOT * KTOT * 2;

    if (ws_size >= need) {
        prep1_kernel<<<NCHUNK + (KTOT / 32) * (NTOT / 32), 256, 0, stream>>>(adj, valid, chunkcnt, kern, kT);
        scan_kernel<<<1, 1024, 0, stream>>>(chunkcnt, chunkoff, nv);
        prep_compact_kernel<<<NCHUNK, 256, 0, stream>>>(valid, chunkoff, feat, abf, cidx, out);
        gemm_kernel<<<(MTOT / BM) * (NTOT / BN), 1024, 0, stream>>>(abf, kT, bias, cidx, nv, out);
    } else {
        transposeB_kernel<<<(KTOT / 32) * (NTOT / 32), 256, 0, stream>>>(kern, kT);
        unsigned short* abf_fb = (unsigned short*)(ws + (2u << 20) + (64u << 10));
        prep_full_kernel<<<MTOT / 4, 256, 0, stream>>>(adj, feat, abf_fb, valid, out);
        gemm_full_kernel<<<(MTOT / BM) * (NTOT / BN), 1024, 0, stream>>>(abf_fb, kT, bias, valid, out);
    }
}